// Round 21
// baseline (67.147 us; speedup 1.0000x reference)
//
#include <hip/hip_runtime.h>
#include <stdint.h>

typedef _Float16 half4_t __attribute__((ext_vector_type(4)));
typedef float    floatx4 __attribute__((ext_vector_type(4)));

static constexpr int HW = 128;
static constexpr int DD = 64;

// nt ONLY on atten loads (read-once input stream, 64MB/dispatch): keeps L2
// dedicated to the reused V panels. r20 lesson: nt on the out store/preload
// RMW path breaks inter-dispatch coherence (stale reads) -> those stay
// normally cached.
#define GLOAD4NT(dst, ptr, o) asm volatile("global_load_dwordx4 %0, %1, off offset:" #o " nt"  : "=v"(dst) : "v"(ptr) : "memory")
#define GLOAD4O(dst, ptr, o)  asm volatile("global_load_dwordx4 %0, %1, off offset:" #o        : "=v"(dst) : "v"(ptr) : "memory")
#define GLOAD1O(dst, ptr, o)  asm volatile("global_load_dword %0, %1, off offset:" #o          : "=v"(dst) : "v"(ptr) : "memory")
#define WAITV(n) do { asm volatile("s_waitcnt vmcnt(" #n ")" ::: "memory"); \
                      __builtin_amdgcn_sched_barrier(0); } while (0)

// Load one k-tile t of V^T A-fragments: dst[i][dt] = v[16t+4g+i][16dt+lr]
// (V is the REUSED stream -> normal caching)
#define LOADT(t_, dst) do { \
    const float* p0_ = vX + (size_t)(16*(t_) + 4*g + 0) * vstr; \
    const float* p1_ = vX + (size_t)(16*(t_) + 4*g + 1) * vstr; \
    const float* p2_ = vX + (size_t)(16*(t_) + 4*g + 2) * vstr; \
    const float* p3_ = vX + (size_t)(16*(t_) + 4*g + 3) * vstr; \
    GLOAD1O(dst[0][0], p0_, 0); GLOAD1O(dst[0][1], p0_, 64); GLOAD1O(dst[0][2], p0_, 128); GLOAD1O(dst[0][3], p0_, 192); \
    GLOAD1O(dst[1][0], p1_, 0); GLOAD1O(dst[1][1], p1_, 64); GLOAD1O(dst[1][2], p1_, 128); GLOAD1O(dst[1][3], p1_, 192); \
    GLOAD1O(dst[2][0], p2_, 0); GLOAD1O(dst[2][1], p2_, 64); GLOAD1O(dst[2][2], p2_, 128); GLOAD1O(dst[2][3], p2_, 192); \
    GLOAD1O(dst[3][0], p3_, 0); GLOAD1O(dst[3][1], p3_, 64); GLOAD1O(dst[3][2], p3_, 128); GLOAD1O(dst[3][3], p3_, 192); \
} while (0)

// One k-tile: convert raw f32 chunk buffer -> half4 A-fragments.
#define CVT1(vf_, c_) do { _Pragma("unroll") for (int dt = 0; dt < 4; ++dt) { \
        vf_[dt][0] = (_Float16)c_[0][dt]; \
        vf_[dt][1] = (_Float16)c_[1][dt]; \
        vf_[dt][2] = (_Float16)c_[2][dt]; \
        vf_[dt][3] = (_Float16)c_[3][dt]; } } while (0)

// D^T = V^T (A) x P^T (B): acc[dt] covers d=16dt+4g+i, c(row)=grow.
#define MFMA1(vf_, t_) do { _Pragma("unroll") for (int dt = 0; dt < 4; ++dt) \
        acc[dt] = __builtin_amdgcn_mfma_f32_16x16x16f16(vf_[dt], af[(t_)], acc[dt], 0, 0, 0); } while (0)

// Block = (brc, half h); 64 output rows; 4 independent waves, 16 rows each.
// NO LDS, NO barrier; pinned-asm counted-vmcnt pipeline, max outstanding 52.
// r18 XCD pair-swizzle (verified: X FETCH 82->49MB, -6us): brc=(d>>4)*8+(d&7),
// h=(d>>3)&1 -> panel siblings n, n+8 share an XCD -> V re-reads L2-local.
// X: brc=(b,r), rows are c, V=v[b,r,:,:] (k-stride 64).   out = P@V
// Y: brc=(b,c), rows are r, V=v[b,:,c,:] (k-stride 8192); out += (preload).
template<bool IS_Y>
__global__ __launch_bounds__(256, 3)
void axial_attn(const float* __restrict__ atten,
                const float* __restrict__ vsrc,
                const float* __restrict__ shift_p,
                float* __restrict__ out)
{
    const int d    = blockIdx.x;
    const int brc  = ((d >> 4) << 3) | (d & 7);   // pair index (b*128+rc)
    const int h    = (d >> 3) & 1;                // half; sibling on same XCD
    const int b    = brc >> 7;
    const int rc   = brc & 127;
    const int tid  = threadIdx.x;
    const int w    = tid >> 6;
    const int lane = tid & 63;
    const int lr   = lane & 15;
    const int g    = lane >> 4;             // 0..3
    const int grow = h * 64 + w * 16 + lr;  // this lane's softmax/output row

    // ---- issue: atten (8x dwordx4 nt, oldest in queue) ----
    const float* arow = atten + (size_t)brc * (HW * HW) + (size_t)grow * HW + g * 4;
    floatx4 a0, a1, a2, a3, a4, a5, a6, a7;
    GLOAD4NT(a0, arow, 0);   GLOAD4NT(a1, arow, 64);  GLOAD4NT(a2, arow, 128); GLOAD4NT(a3, arow, 192);
    GLOAD4NT(a4, arow, 256); GLOAD4NT(a5, arow, 320); GLOAD4NT(a6, arow, 384); GLOAD4NT(a7, arow, 448);

    const float* vX   = IS_Y ? vsrc + ((size_t)b * HW * HW + rc) * DD + lr
                             : vsrc + (size_t)brc * (HW * DD) + lr;
    const int    vstr = IS_Y ? HW * DD : DD;

    // ---- issue: Y out-preload (4x dwordx4, cached), then V chunks 0,1 ----
    float* ob = IS_Y ? out + (size_t)b * (HW * HW * DD) + (size_t)grow * (HW * DD) + rc * DD
                     : out + (size_t)brc * (HW * DD) + (size_t)grow * DD;
    floatx4 acc[4];
    if (IS_Y) {
        const float* pb = ob + 4 * g;
        GLOAD4O(acc[0], pb, 0); GLOAD4O(acc[1], pb, 64);
        GLOAD4O(acc[2], pb, 128); GLOAD4O(acc[3], pb, 192);
    } else {
        #pragma unroll
        for (int dt = 0; dt < 4; ++dt) acc[dt] = (floatx4)(0.f);
    }

    float cb0[4][4], cb1[4][4], cb2[4][4], cb3[4][4];   // rotating chunk buffers
    LOADT(0, cb0); LOADT(1, cb1);

    // ---- wait: atten only (X: c0,c1=32 left; Y: P+c0,c1=36 left) ----
    if constexpr (IS_Y) { WAITV(36); } else { WAITV(32); }

    const float shift = shift_p[0];         // bias cancels in softmax

    // ---- in-register softmax of row `grow` (logits in place over atten regs) ----
    floatx4 av[8] = {a0, a1, a2, a3, a4, a5, a6, a7};
    #pragma unroll
    for (int t = 0; t < 8; ++t)
        #pragma unroll
        for (int i = 0; i < 4; ++i) {
            const float dd = (float)(16 * t + 4 * g + i - grow);
            av[t][i] = fmaf(-shift * dd, dd, av[t][i]);
        }
    float m16[16];
    #pragma unroll
    for (int i = 0; i < 16; ++i) m16[i] = fmaxf(av[i >> 2][i & 3], av[4 + (i >> 2)][i & 3]);
    #pragma unroll
    for (int s = 8; s >= 1; s >>= 1)
        #pragma unroll
        for (int i = 0; i < s; ++i) m16[i] = fmaxf(m16[i], m16[i + s]);
    float mx = m16[0];
    mx = fmaxf(mx, __shfl_xor(mx, 16));
    mx = fmaxf(mx, __shfl_xor(mx, 32));

    float e[32];
    #pragma unroll
    for (int t = 0; t < 8; ++t)
        #pragma unroll
        for (int i = 0; i < 4; ++i) e[t * 4 + i] = __expf(av[t][i] - mx);
    float s16[16];
    #pragma unroll
    for (int i = 0; i < 16; ++i) s16[i] = e[i] + e[i + 16];
    #pragma unroll
    for (int s = 8; s >= 1; s >>= 1)
        #pragma unroll
        for (int i = 0; i < s; ++i) s16[i] += s16[i + s];
    float sum = s16[0];
    sum += __shfl_xor(sum, 16);
    sum += __shfl_xor(sum, 32);
    const float inv = 1.0f / sum;

    // ---- issue: c2 now (outstanding: X 48, Y 52 <= 63) ----
    LOADT(2, cb2);

    half4_t af[8];                           // P A-frag == P^T B-frag (same lane map)
    #pragma unroll
    for (int t = 0; t < 8; ++t)
        #pragma unroll
        for (int i = 0; i < 4; ++i)
            af[t][i] = (_Float16)(e[4 * t + i] * inv);

    // ---- 8 phases; one chunk drained per phase, one issued (ph0-4) ----
    half4_t vf[4];
    WAITV(32); CVT1(vf, cb0); MFMA1(vf, 0); LOADT(3, cb3);   // drain c0 (+Y pre)
    WAITV(32); CVT1(vf, cb1); MFMA1(vf, 1); LOADT(4, cb0);   // drain c1
    WAITV(32); CVT1(vf, cb2); MFMA1(vf, 2); LOADT(5, cb1);   // drain c2
    WAITV(32); CVT1(vf, cb3); MFMA1(vf, 3); LOADT(6, cb2);   // drain c3
    WAITV(32); CVT1(vf, cb0); MFMA1(vf, 4); LOADT(7, cb3);   // drain c4
    WAITV(32); CVT1(vf, cb1); MFMA1(vf, 5);                  // drain c5
    WAITV(16); CVT1(vf, cb2); MFMA1(vf, 6);                  // drain c6
    WAITV(0);  CVT1(vf, cb3); MFMA1(vf, 7);                  // drain c7

    // ---- store (cached): lane holds out[row=grow][d=16dt+4g+i] ----
    #pragma unroll
    for (int dt = 0; dt < 4; ++dt)
        *(floatx4*)&ob[16 * dt + 4 * g] = acc[dt];
}

extern "C" void kernel_launch(void* const* d_in, const int* in_sizes, int n_in,
                              void* d_out, int out_size, void* d_ws, size_t ws_size,
                              hipStream_t stream)
{
    // inputs: 0=x (unused), 1=atten_x_full, 2=atten_y_full, 3=value_full, 4=shift, 5=bias (cancels)
    const float* atx   = (const float*)d_in[1];
    const float* aty   = (const float*)d_in[2];
    const float* val   = (const float*)d_in[3];
    const float* shift = (const float*)d_in[4];
    float* out = (float*)d_out;

    axial_attn<false><<<dim3(8 * 128 * 2), dim3(256), 0, stream>>>(atx, val, shift, out);
    axial_attn<true ><<<dim3(8 * 128 * 2), dim3(256), 0, stream>>>(aty, val, shift, out);
}

// Round 22
// 53.901 us; speedup vs baseline: 1.2458x; 1.2458x over previous
//
#include <hip/hip_runtime.h>
#include <stdint.h>

typedef _Float16 half4_t __attribute__((ext_vector_type(4)));
typedef float    floatx4 __attribute__((ext_vector_type(4)));

static constexpr int HW = 128;
static constexpr int DD = 64;

#define GLOAD4O(dst, ptr, o) asm volatile("global_load_dwordx4 %0, %1, off offset:" #o : "=v"(dst) : "v"(ptr) : "memory")
#define GLOAD1O(dst, ptr, o) asm volatile("global_load_dword %0, %1, off offset:" #o   : "=v"(dst) : "v"(ptr) : "memory")
#define WAITV(n) do { asm volatile("s_waitcnt vmcnt(" #n ")" ::: "memory"); \
                      __builtin_amdgcn_sched_barrier(0); } while (0)

// Load one k-tile t of V^T A-fragments: dst[i][dt] = v[16t+4g+i][16dt+lr]
#define LOADT(t_, dst) do { \
    const float* p0_ = vX + (size_t)(16*(t_) + 4*g + 0) * vstr; \
    const float* p1_ = vX + (size_t)(16*(t_) + 4*g + 1) * vstr; \
    const float* p2_ = vX + (size_t)(16*(t_) + 4*g + 2) * vstr; \
    const float* p3_ = vX + (size_t)(16*(t_) + 4*g + 3) * vstr; \
    GLOAD1O(dst[0][0], p0_, 0); GLOAD1O(dst[0][1], p0_, 64); GLOAD1O(dst[0][2], p0_, 128); GLOAD1O(dst[0][3], p0_, 192); \
    GLOAD1O(dst[1][0], p1_, 0); GLOAD1O(dst[1][1], p1_, 64); GLOAD1O(dst[1][2], p1_, 128); GLOAD1O(dst[1][3], p1_, 192); \
    GLOAD1O(dst[2][0], p2_, 0); GLOAD1O(dst[2][1], p2_, 64); GLOAD1O(dst[2][2], p2_, 128); GLOAD1O(dst[2][3], p2_, 192); \
    GLOAD1O(dst[3][0], p3_, 0); GLOAD1O(dst[3][1], p3_, 64); GLOAD1O(dst[3][2], p3_, 128); GLOAD1O(dst[3][3], p3_, 192); \
} while (0)

// One k-tile: convert raw f32 chunk buffer -> half4 A-fragments.
#define CVT1(vf_, c_) do { _Pragma("unroll") for (int dt = 0; dt < 4; ++dt) { \
        vf_[dt][0] = (_Float16)c_[0][dt]; \
        vf_[dt][1] = (_Float16)c_[1][dt]; \
        vf_[dt][2] = (_Float16)c_[2][dt]; \
        vf_[dt][3] = (_Float16)c_[3][dt]; } } while (0)

// D^T = V^T (A) x P^T (B): acc[dt] covers d=16dt+4g+i, c(row)=grow.
#define MFMA1(vf_, t_) do { _Pragma("unroll") for (int dt = 0; dt < 4; ++dt) \
        acc[dt] = __builtin_amdgcn_mfma_f32_16x16x16f16(vf_[dt], af[(t_)], acc[dt], 0, 0, 0); } while (0)

// FINAL (r18 revert — measured optimum 54.0us):
// Block = (brc, half h); 64 output rows; 4 independent waves, 16 rows each.
// NO LDS, NO barrier; pinned-asm counted-vmcnt pipeline, max outstanding 52.
// XCD pair-swizzle (verified: X FETCH 82->49MB, -6us): brc=(d>>4)*8+(d&7),
// h=(d>>3)&1 -> panel siblings n, n+8 share an XCD -> V re-reads L2-local.
// In-register softmax in MFMA A-frag layout serves directly as the B operand
// (P^T) via D^T = V^T x P^T (identical per-lane element map).
// X: brc=(b,r), rows are c, V=v[b,r,:,:] (k-stride 64).   out = P@V
// Y: brc=(b,c), rows are r, V=v[b,:,c,:] (k-stride 8192); out += (preload).
//
// Mutation record (all regressed; do not revisit):
//   deeper pipeline r11 flat · occupancy-force r14/16 spill-clobber crash ·
//   prefetch-relocation r10/r13 -8us · atomic fusion r17 -175us ·
//   batch-XCD pin r19 -1.4us · nt stores r20 stale-read FAIL · nt loads r21 -13us.
template<bool IS_Y>
__global__ __launch_bounds__(256, 3)
void axial_attn(const float* __restrict__ atten,
                const float* __restrict__ vsrc,
                const float* __restrict__ shift_p,
                float* __restrict__ out)
{
    const int d    = blockIdx.x;
    const int brc  = ((d >> 4) << 3) | (d & 7);   // pair index (b*128+rc)
    const int h    = (d >> 3) & 1;                // half; sibling on same XCD
    const int b    = brc >> 7;
    const int rc   = brc & 127;
    const int tid  = threadIdx.x;
    const int w    = tid >> 6;
    const int lane = tid & 63;
    const int lr   = lane & 15;
    const int g    = lane >> 4;             // 0..3
    const int grow = h * 64 + w * 16 + lr;  // this lane's softmax/output row

    // ---- issue: atten (8x dwordx4, oldest in queue) ----
    const float* arow = atten + (size_t)brc * (HW * HW) + (size_t)grow * HW + g * 4;
    floatx4 a0, a1, a2, a3, a4, a5, a6, a7;
    GLOAD4O(a0, arow, 0);   GLOAD4O(a1, arow, 64);  GLOAD4O(a2, arow, 128); GLOAD4O(a3, arow, 192);
    GLOAD4O(a4, arow, 256); GLOAD4O(a5, arow, 320); GLOAD4O(a6, arow, 384); GLOAD4O(a7, arow, 448);

    const float* vX   = IS_Y ? vsrc + ((size_t)b * HW * HW + rc) * DD + lr
                             : vsrc + (size_t)brc * (HW * DD) + lr;
    const int    vstr = IS_Y ? HW * DD : DD;

    // ---- issue: Y out-preload (4x dwordx4), then V chunks 0,1 ----
    float* ob = IS_Y ? out + (size_t)b * (HW * HW * DD) + (size_t)grow * (HW * DD) + rc * DD
                     : out + (size_t)brc * (HW * DD) + (size_t)grow * DD;
    floatx4 acc[4];
    if (IS_Y) {
        const float* pb = ob + 4 * g;
        GLOAD4O(acc[0], pb, 0); GLOAD4O(acc[1], pb, 64);
        GLOAD4O(acc[2], pb, 128); GLOAD4O(acc[3], pb, 192);
    } else {
        #pragma unroll
        for (int dt = 0; dt < 4; ++dt) acc[dt] = (floatx4)(0.f);
    }

    float cb0[4][4], cb1[4][4], cb2[4][4], cb3[4][4];   // rotating chunk buffers
    LOADT(0, cb0); LOADT(1, cb1);

    // ---- wait: atten only (X: c0,c1=32 left; Y: P+c0,c1=36 left) ----
    if constexpr (IS_Y) { WAITV(36); } else { WAITV(32); }

    const float shift = shift_p[0];         // bias cancels in softmax

    // ---- in-register softmax of row `grow` (logits in place over atten regs) ----
    floatx4 av[8] = {a0, a1, a2, a3, a4, a5, a6, a7};
    #pragma unroll
    for (int t = 0; t < 8; ++t)
        #pragma unroll
        for (int i = 0; i < 4; ++i) {
            const float dd = (float)(16 * t + 4 * g + i - grow);
            av[t][i] = fmaf(-shift * dd, dd, av[t][i]);
        }
    float m16[16];
    #pragma unroll
    for (int i = 0; i < 16; ++i) m16[i] = fmaxf(av[i >> 2][i & 3], av[4 + (i >> 2)][i & 3]);
    #pragma unroll
    for (int s = 8; s >= 1; s >>= 1)
        #pragma unroll
        for (int i = 0; i < s; ++i) m16[i] = fmaxf(m16[i], m16[i + s]);
    float mx = m16[0];
    mx = fmaxf(mx, __shfl_xor(mx, 16));
    mx = fmaxf(mx, __shfl_xor(mx, 32));

    float e[32];
    #pragma unroll
    for (int t = 0; t < 8; ++t)
        #pragma unroll
        for (int i = 0; i < 4; ++i) e[t * 4 + i] = __expf(av[t][i] - mx);
    float s16[16];
    #pragma unroll
    for (int i = 0; i < 16; ++i) s16[i] = e[i] + e[i + 16];
    #pragma unroll
    for (int s = 8; s >= 1; s >>= 1)
        #pragma unroll
        for (int i = 0; i < s; ++i) s16[i] += s16[i + s];
    float sum = s16[0];
    sum += __shfl_xor(sum, 16);
    sum += __shfl_xor(sum, 32);
    const float inv = 1.0f / sum;

    // ---- issue: c2 now (outstanding: X 48, Y 52 <= 63) ----
    LOADT(2, cb2);

    half4_t af[8];                           // P A-frag == P^T B-frag (same lane map)
    #pragma unroll
    for (int t = 0; t < 8; ++t)
        #pragma unroll
        for (int i = 0; i < 4; ++i)
            af[t][i] = (_Float16)(e[4 * t + i] * inv);

    // ---- 8 phases; one chunk drained per phase, one issued (ph0-4) ----
    half4_t vf[4];
    WAITV(32); CVT1(vf, cb0); MFMA1(vf, 0); LOADT(3, cb3);   // drain c0 (+Y pre)
    WAITV(32); CVT1(vf, cb1); MFMA1(vf, 1); LOADT(4, cb0);   // drain c1
    WAITV(32); CVT1(vf, cb2); MFMA1(vf, 2); LOADT(5, cb1);   // drain c2
    WAITV(32); CVT1(vf, cb3); MFMA1(vf, 3); LOADT(6, cb2);   // drain c3
    WAITV(32); CVT1(vf, cb0); MFMA1(vf, 4); LOADT(7, cb3);   // drain c4
    WAITV(32); CVT1(vf, cb1); MFMA1(vf, 5);                  // drain c5
    WAITV(16); CVT1(vf, cb2); MFMA1(vf, 6);                  // drain c6
    WAITV(0);  CVT1(vf, cb3); MFMA1(vf, 7);                  // drain c7

    // ---- store: lane holds out[row=grow][d=16dt+4g+i] -> 4x dwordx4 ----
    #pragma unroll
    for (int dt = 0; dt < 4; ++dt)
        *(floatx4*)&ob[16 * dt + 4 * g] = acc[dt];
}

extern "C" void kernel_launch(void* const* d_in, const int* in_sizes, int n_in,
                              void* d_out, int out_size, void* d_ws, size_t ws_size,
                              hipStream_t stream)
{
    // inputs: 0=x (unused), 1=atten_x_full, 2=atten_y_full, 3=value_full, 4=shift, 5=bias (cancels)
    const float* atx   = (const float*)d_in[1];
    const float* aty   = (const float*)d_in[2];
    const float* val   = (const float*)d_in[3];
    const float* shift = (const float*)d_in[4];
    float* out = (float*)d_out;

    axial_attn<false><<<dim3(8 * 128 * 2), dim3(256), 0, stream>>>(atx, val, shift, out);
    axial_attn<true ><<<dim3(8 * 128 * 2), dim3(256), 0, stream>>>(aty, val, shift, out);
}